// Round 13
// baseline (565.757 us; speedup 1.0000x reference)
//
#include <hip/hip_runtime.h>

// LinearAttention (fp32 in/out, bf16 internal MFMA):
// x(8,64,64,256) f32, w_qkv(256,1536) f32, gn_scale/bias(512) f32,
// w_out(512,256) f32, b_out(256) f32 -> out(8,64,64,256) f32
// B=8, N=4096 tokens/batch, HEADS=8, DH=64, HID=512, DIM=256.
//
// Softmaxes WITHOUT max subtraction (|q|,|k| <~ 6, exp fp32-safe).
// R2: kvctx fuses kv-GEMM + exp + ctx partials (kvT eliminated).
// R5: XCD co-location for kvctx (grid FROZEN at 2048 -- R10 regrid
// collapsed L2 sharing). R6: 2-phase pipelined K-loops (BK=32 dbuf).
// R7: prep fused, finalize folded into final GEMM. R11: tile-major A2.
// R12: gemm_out 64-row tiles, dim3(2,512).
// R13: reduce_kernel ELIMINATED -- fused into kvctx via the threadfence +
//      atomic-counter "last block per bh reduces" pattern (device-scope,
//      guide G12/G16). The 32nd-arriving block for each bh folds the 32
//      ctxP chunks (same c=0..31 order -> bit-identical) and writes ctxB.
//      Removes one launch boundary + one cold 34MB re-read pass.
// GN folded into final GEMM. 4 launches + memset.

typedef unsigned short ushort_t;
typedef __attribute__((ext_vector_type(8))) short short8;
typedef __attribute__((ext_vector_type(4))) float floatx4;

__device__ __forceinline__ ushort_t f2b(float f) {
  unsigned int i;
  __builtin_memcpy(&i, &f, 4);
  unsigned int r = (i + 0x7FFFu + ((i >> 16) & 1u)) >> 16;
  return (ushort_t)r;
}

// async 16B global->LDS copy (HW dest = wave-uniform base + lane*16)
__device__ __forceinline__ void load_lds16(const ushort_t* g, ushort_t* l) {
  __builtin_amdgcn_global_load_lds(
      (const __attribute__((address_space(1))) unsigned int*)g,
      (__attribute__((address_space(3))) unsigned int*)l, 16, 0, 0);
}

// ---------------------------------------------------------------------------
// FUSED prep: blocks [0,8192) cast x->xb; [8192,8576) transpose w_qkv;
// [8576,8704) transpose w_out (gn_scale-folded); [8704] prep_gw.
// ---------------------------------------------------------------------------
__global__ __launch_bounds__(256) void prep_all(
    const float* __restrict__ x, const float* __restrict__ w_qkv,
    const float* __restrict__ gn_scale, const float* __restrict__ gn_bias,
    const float* __restrict__ w_out, const float* __restrict__ b_out,
    ushort_t* __restrict__ xb, ushort_t* __restrict__ wqkvT,
    ushort_t* __restrict__ w2T, float* __restrict__ gw1,
    float* __restrict__ bias2) {
  __shared__ ushort_t t[32][33];
  int bid = blockIdx.x;
  if (bid < 8192) {  // cast f32 -> bf16
    long i = ((long)bid * 256 + threadIdx.x) * 4;
    float4 v = *(const float4*)(x + i);
    ushort4 o;
    o.x = f2b(v.x);
    o.y = f2b(v.y);
    o.z = f2b(v.z);
    o.w = f2b(v.w);
    *(ushort4*)(xb + i) = o;
    return;
  }
  bid -= 8192;
  if (bid < 384) {  // transpose w_qkv (256x1536) -> wqkvT (1536x256)
    int c0 = (bid % 48) * 32, r0 = (bid / 48) * 32;
    int tx = threadIdx.x & 31, ty = threadIdx.x >> 5;
    for (int i = 0; i < 32; i += 8)
      t[ty + i][tx] = f2b(w_qkv[(long)(r0 + ty + i) * 1536 + c0 + tx]);
    __syncthreads();
    for (int i = 0; i < 32; i += 8)
      wqkvT[(long)(c0 + ty + i) * 256 + r0 + tx] = t[tx][ty + i];
    return;
  }
  bid -= 384;
  if (bid < 128) {  // transpose w_out (512x256) -> w2T, gn_scale-folded
    int c0 = (bid % 8) * 32, r0 = (bid / 8) * 32;
    int tx = threadIdx.x & 31, ty = threadIdx.x >> 5;
    for (int i = 0; i < 32; i += 8) {
      float s = gn_scale[r0 + ty + i];
      t[ty + i][tx] = f2b(w_out[(long)(r0 + ty + i) * 256 + c0 + tx] * s);
    }
    __syncthreads();
    for (int i = 0; i < 32; i += 8)
      w2T[(long)(c0 + ty + i) * 512 + r0 + tx] = t[tx][ty + i];
    return;
  }
  // last block: prep_gw (c = 0..255)
  int c = threadIdx.x;
  float g1 = 0.f, b2 = 0.f;
  for (int f = 0; f < 512; ++f) {
    float w = w_out[f * 256 + c];
    g1 += gn_scale[f] * w;
    b2 += gn_bias[f] * w;
  }
  gw1[c] = g1;
  bias2[c] = b2 + b_out[c];
}

// ---------------------------------------------------------------------------
// FUSED k/v-GEMM + exp + ctx-partial + LAST-BLOCK fused reduce.
// Grid 2048 1-D (FROZEN): gid = (b*32+cy) + 256*h -> gid%8 = cy%8,
// head-blocks sharing an xb slice co-locate on one XCD.
// K-loop: 8 iters BK=32, dbuf in 32KB; iter t stages t+1 THEN computes t.
// Epilogue: exp(k) in-register, ctx-swizzled kTs/vTs round trip, ctx MFMA
// (+ones ksum), NON-ATOMIC partials (32 chunks). Then: threadfence +
// atomicAdd(done[bh]); the 32nd arriver folds all chunks -> ctxB
// (kinv-scaled, bf16, MFMA-swizzled), bit-identical c=0..31 sum order.
// ---------------------------------------------------------------------------
__global__ __launch_bounds__(256, 4) void kvctx_kernel(
    const ushort_t* __restrict__ xb, const ushort_t* __restrict__ wqkvT,
    float* __restrict__ ctxP, float* __restrict__ ksumP,
    ushort_t* __restrict__ ctxB, unsigned int* __restrict__ done) {
  __shared__ __align__(16) char lds[32768];
  __shared__ int sh_last;
  ushort_t* kTs = (ushort_t*)lds;            // [64 d][128 n] (epilogue alias)
  ushort_t* vTs = (ushort_t*)(lds + 16384);  // [64 e][128 n]

  int gid = blockIdx.x;
  int h = gid >> 8;      // 0..7
  int c0i = gid & 255;   // b*32 + cy
  int b = c0i >> 5;      // 0..7
  int cy = c0i & 31;     // 0..31
  int bh = b * 8 + h;
  int tid = threadIdx.x, wv = tid >> 6, lane = tid & 63;
  int wm = wv & 1, wfk = wv >> 1;  // token half / k-vs-v half
  int l15 = lane & 15, quad = lane >> 4;
  long m0 = (long)b * 4096 + cy * 128;

  floatx4 zero = {0.f, 0.f, 0.f, 0.f};
  floatx4 acc[4][4];
  for (int i = 0; i < 4; i++)
    for (int j = 0; j < 4; j++) acc[i][j] = zero;

  auto stage = [&](int p, int k0) {
    ushort_t* Ab = (ushort_t*)(lds + p * 16384);
    ushort_t* Bb = Ab + 4096;  // +8KB
#pragma unroll
    for (int r = 0; r < 2; ++r) {
      int chunk = r * 256 + tid;
      int row = chunk >> 2, kc = chunk & 3;
      int gc = kc ^ (row & 3);
      long arow = (row < 64 ? 512 : 960) + h * 64 + row;
      load_lds16(wqkvT + arow * 256 + k0 + gc * 8, Ab + chunk * 8);
      load_lds16(xb + (m0 + row) * 256 + k0 + gc * 8, Bb + chunk * 8);
    }
  };

  stage(0, 0);
  __syncthreads();
#pragma unroll
  for (int t = 0; t < 8; ++t) {
    int p = t & 1;
    if (t < 7) stage(p ^ 1, (t + 1) * 32);  // prefetch next tile
    ushort_t* Ab = (ushort_t*)(lds + p * 16384);
    ushort_t* Bb = Ab + 4096;
    short8 af[4], bfr[4];
#pragma unroll
    for (int mt = 0; mt < 4; mt++) {
      int row = wfk * 64 + mt * 16 + l15;
      int slot = quad ^ (row & 3);
      af[mt] = *(const short8*)(Ab + row * 32 + slot * 8);
    }
#pragma unroll
    for (int ft = 0; ft < 4; ft++) {
      int rowb = wm * 64 + ft * 16 + l15;
      int slot = quad ^ (rowb & 3);
      bfr[ft] = *(const short8*)(Bb + rowb * 32 + slot * 8);
    }
#pragma unroll
    for (int mt = 0; mt < 4; mt++)
#pragma unroll
      for (int ft = 0; ft < 4; ft++)
        acc[mt][ft] = __builtin_amdgcn_mfma_f32_16x16x32_bf16(
            af[mt], bfr[ft], acc[mt][ft], 0, 0, 0);
    __syncthreads();  // prefetch landed + everyone done reading buf p
  }
  // loop ended with barrier: staging dead, reusable as kTs/vTs

  // write kv tile into ctx-swizzled LDS layout; exp on the k half.
  {
    ushort_t* T = wfk ? vTs : kTs;
#pragma unroll
    for (int mt = 0; mt < 4; mt++)
#pragma unroll
      for (int ft = 0; ft < 4; ft++) {
        int n = wm * 64 + ft * 16 + l15;
        int c = n >> 3, u = n & 7;
#pragma unroll
        for (int r = 0; r < 4; r++) {
          int d = mt * 16 + quad * 4 + r;
          float v = acc[mt][ft][r];
          if (!wfk) v = __expf(v);
          int slot = (c & 8) | ((c ^ d) & 7);
          T[d * 128 + slot * 8 + u] = f2b(v);
        }
      }
  }
  __syncthreads();  // kTs/vTs visible to all waves

  // ctx partial: ctx[d][e] = sum_n exp(k[d,n]) * v[e,n]; ksum via ones-MFMA
  floatx4 cacc[4], acc1;
  for (int i = 0; i < 4; i++) cacc[i] = zero;
  acc1 = zero;
  short8 ones;
#pragma unroll
  for (int u = 0; u < 8; ++u) ones[u] = (short)0x3F80;  // bf16 1.0
#pragma unroll
  for (int ks = 0; ks < 4; ++ks) {
    int d = wv * 16 + l15;
    int cidx = ks * 4 + quad;
    int sa = (cidx & 8) | ((cidx ^ d) & 7);
    short8 a = *(const short8*)(kTs + d * 128 + sa * 8);
    short8 bf[4];
#pragma unroll
    for (int ft = 0; ft < 4; ++ft) {
      int e = ft * 16 + l15;
      int sb = (cidx & 8) | ((cidx ^ e) & 7);
      bf[ft] = *(const short8*)(vTs + e * 128 + sb * 8);
    }
#pragma unroll
    for (int ft = 0; ft < 4; ++ft)
      cacc[ft] = __builtin_amdgcn_mfma_f32_16x16x32_bf16(a, bf[ft], cacc[ft],
                                                         0, 0, 0);
    acc1 = __builtin_amdgcn_mfma_f32_16x16x32_bf16(a, ones, acc1, 0, 0, 0);
  }
  float* cb = ctxP + ((long)cy * 64 + bh) * 4096;
#pragma unroll
  for (int ft = 0; ft < 4; ++ft)
    *(floatx4*)&cb[(ft * 16 + l15) * 64 + wv * 16 + quad * 4] = cacc[ft];
  if (l15 == 0) {
    float* kb = ksumP + ((long)cy * 64 + bh) * 64;
    *(floatx4*)&kb[wv * 16 + quad * 4] = acc1;
  }

  // --- last-block-per-bh fused reduce (replaces reduce_kernel) ---
  __threadfence();  // release: make this block's partials device-visible
  if (tid == 0) sh_last = (atomicAdd(&done[bh], 1u) == 31u);
  __syncthreads();  // broadcast sh_last; also: LDS reads above complete
  if (!sh_last) return;
  __threadfence();  // acquire: observe all 32 blocks' partials

  // ksum fold -> 1/ks in LDS (staging region dead)
  float* ksLds = (float*)lds;
  if (tid < 64) {
    float ks = 0.f;
#pragma unroll
    for (int c = 0; c < 32; ++c) ks += ksumP[((long)c * 64 + bh) * 64 + tid];
    ksLds[tid] = 1.0f / ks;
  }
  __syncthreads();

  // fold 32 chunks, 16 consecutive j per thread (4 x float4, coalesced)
  int j0 = tid * 16;
#pragma unroll
  for (int q4 = 0; q4 < 4; ++q4) {
    floatx4 s = zero;
#pragma unroll
    for (int c = 0; c < 32; ++c)
      s = s + *(const floatx4*)&ctxP[((long)c * 64 + bh) * 4096 + j0 + q4 * 4];
#pragma unroll
    for (int k = 0; k < 4; ++k) {
      int j = j0 + q4 * 4 + k;
      int e = j >> 6, d = j & 63;
      int slot = (d >> 3) ^ (e & 7);
      ctxB[(long)bh * 4096 + e * 64 + slot * 8 + (d & 7)] =
          f2b(s[k] * ksLds[d]);
    }
  }
}

// ---------------------------------------------------------------------------
// FUSED q-GEMM + q-softmax + P@ctx, 2-phase pipelined K-loop (BK=32 dbuf).
// Grid (256 token-tiles, 4 col-tiles), 4 blk/CU. Epilogue: ctxB frags
// global->reg; exp in-register; butterfly row-sums; 0.125/s folded into P
// bf16 write; P round-trip via per-wave LDS; P@ctx MFMA (K=64); o tile
// repacked via LDS (Od). A2 TILE-MAJOR [bx][by][128][128].
// ---------------------------------------------------------------------------
__global__ __launch_bounds__(256, 4) void qattn_kernel(
    const ushort_t* __restrict__ xb, const ushort_t* __restrict__ wqT,
    const ushort_t* __restrict__ ctxB, ushort_t* __restrict__ A2,
    float* __restrict__ gstats) {
  __shared__ __align__(16) char lds[32800];
  ushort_t* P = (ushort_t*)lds;        // [2][128][64] per-wave scratch
  ushort_t* Od = (ushort_t*)lds;       // [128][128] repack (epilogue)
  float* red = (float*)(lds + 32768);  // [8]

  int tid = threadIdx.x;
  int bx = blockIdx.x, by = blockIdx.y;
  long m0 = (long)bx * 128;
  long f0 = (long)by * 128;
  int wv = tid >> 6, lane = tid & 63;
  int wm = wv & 1, wf = wv >> 1;
  int l15 = lane & 15, quad = lane >> 4;
  int b = bx >> 5;  // 32 tiles of 128 tokens per batch

  floatx4 acc[4][4];
  floatx4 zero = {0.f, 0.f, 0.f, 0.f};
  for (int i = 0; i < 4; i++)
    for (int j = 0; j < 4; j++) acc[i][j] = zero;

  auto stage = [&](int p, int k0) {
    ushort_t* Ab = (ushort_t*)(lds + p * 16384);
    ushort_t* Bb = Ab + 4096;  // +8KB
#pragma unroll
    for (int r = 0; r < 2; ++r) {
      int chunk = r * 256 + tid;
      int row = chunk >> 2, kc = chunk & 3;
      int gc = kc ^ (row & 3);
      load_lds16(xb + (m0 + row) * 256 + k0 + gc * 8, Ab + chunk * 8);
      load_lds16(wqT + (f0 + row) * 256 + k0 + gc * 8, Bb + chunk * 8);
    }
  };

  stage(0, 0);
  __syncthreads();
#pragma unroll
  for (int t = 0; t < 8; ++t) {
    int p = t & 1;
    if (t < 7) stage(p ^ 1, (t + 1) * 32);  // prefetch next tile
    ushort_t* Ab = (ushort_t*)(lds + p * 16384);
    ushort_t* Bb = Ab + 4096;
    short8 af[4], bfr[4];
#pragma unroll
    for (int mt = 0; mt < 4; mt++) {
      int row = wm * 64 + mt * 16 + l15;
      int slot = quad ^ (row & 3);
      af[mt] = *(const short8*)(Ab + row * 32 + slot * 8);
    }
#pragma unroll
    for (int ft = 0; ft < 4; ft++) {
      int rowb = wf * 64 + ft * 16 + l15;
      int slot = quad ^ (rowb & 3);
      bfr[ft] = *(const short8*)(Bb + rowb * 32 + slot * 8);
    }
#pragma unroll
    for (int mt = 0; mt < 4; mt++)
#pragma unroll
      for (int ft = 0; ft < 4; ft++)
        acc[mt][ft] = __builtin_amdgcn_mfma_f32_16x16x32_bf16(
            af[mt], bfr[ft], acc[mt][ft], 0, 0, 0);
    __syncthreads();
  }
  // loop ended with barrier: staging dead, safe to reuse as P

  // ctxB fragments (k0=0 half) global->reg (L2-resident)
  const ushort_t* cg = ctxB + ((long)(b * 8 + by * 2 + wf)) * 4096;
  short8 cfr0[4];
#pragma unroll
  for (int ft = 0; ft < 4; ++ft) {
    int e = ft * 16 + l15;
    int slot = quad ^ (e & 7);
    cfr0[ft] = *(const short8*)(cg + e * 64 + slot * 8);
  }

  // exp in-register + row sums (butterfly over l15) -> rs = 0.125/s
  float rs[4][4];
#pragma unroll
  for (int mt = 0; mt < 4; mt++)
#pragma unroll
    for (int r = 0; r < 4; r++) rs[mt][r] = 0.f;
#pragma unroll
  for (int mt = 0; mt < 4; mt++)
#pragma unroll
    for (int ft = 0; ft < 4; ft++)
#pragma unroll
      for (int r = 0; r < 4; r++) {
        float e = __expf(acc[mt][ft][r]);
        acc[mt][ft][r] = e;
        rs[mt][r] += e;
      }
#pragma unroll
  for (int mt = 0; mt < 4; mt++)
#pragma unroll
    for (int r = 0; r < 4; r++) {
      float t = rs[mt][r];
      t += __shfl_xor(t, 1);
      t += __shfl_xor(t, 2);
      t += __shfl_xor(t, 4);
      t += __shfl_xor(t, 8);
      rs[mt][r] = 0.125f / t;
    }

  // write P = exp * rs to per-wave LDS scratch in swizzled A-layout
  {
    ushort_t* Pw = P + wf * 8192;
#pragma unroll
    for (int mt = 0; mt < 4; mt++)
#pragma unroll
      for (int ft = 0; ft < 4; ft++) {
        int d = ft * 16 + l15;
#pragma unroll
        for (int r = 0; r < 4; r++) {
          int row = wm * 64 + mt * 16 + quad * 4 + r;
          int slot = (d >> 3) ^ (row & 7);
          Pw[row * 64 + slot * 8 + (d & 7)] = f2b(acc[mt][ft][r] * rs[mt][r]);
        }
      }
  }

  // ctxB fragments (k0=1 half)
  short8 cfr1[4];
#pragma unroll
  for (int ft = 0; ft < 4; ++ft) {
    int e = ft * 16 + l15;
    int slot = (4 + quad) ^ (e & 7);
    cfr1[ft] = *(const short8*)(cg + e * 64 + slot * 8);
  }

  // P@ctx MFMA: K=64. P per-wave private -> no barrier needed.
  floatx4 o[4][4];
  for (int i = 0; i < 4; i++)
    for (int j = 0; j < 4; j++) o[i][j] = zero;
  {
    const ushort_t* Pr = P + wf * 8192;
    short8 af[4];
#pragma unroll
    for (int mt = 0; mt < 4; mt++) {
      int row = wm * 64 + mt * 16 + l15;
      int slot = quad ^ (row & 7);
      af[mt] = *(const short8*)(Pr + row * 64 + slot * 8);
    }
#pragma unroll
    for (int mt = 0; mt < 4; mt++)
#pragma unroll
      for (int ft = 0; ft < 4; ft++)
        o[mt][ft] = __builtin_amdgcn_mfma_f32_16x16x32_bf16(af[mt], cfr0[ft],
                                                            o[mt][ft], 0, 0,
                                                            0);
#pragma unroll
    for (int mt = 0; mt < 4; mt++) {
      int row = wm * 64 + mt * 16 + l15;
      int slot = (4 + quad) ^ (row & 7);
      af[mt] = *(const short8*)(Pr + row * 64 + slot * 8);
    }
#pragma unroll
    for (int mt = 0; mt < 4; mt++)
#pragma unroll
      for (int ft = 0; ft < 4; ft++)
        o[mt][ft] = __builtin_amdgcn_mfma_f32_16x16x32_bf16(af[mt], cfr1[ft],
                                                            o[mt][ft], 0, 0,
                                                            0);
  }

  // GN stats from o (these ARE the final A2 values)
  float lsum = 0.f, lss = 0.f;
#pragma unroll
  for (int mt = 0; mt < 4; mt++)
#pragma unroll
    for (int ft = 0; ft < 4; ft++)
#pragma unroll
      for (int r = 0; r < 4; r++) {
        float v = o[mt][ft][r];
        lsum += v;
        lss += v * v;
      }

  __syncthreads();  // all P reads done; P region reusable as Od repack

  // repack o into Od[128][128] (chunk-swizzled), then contiguous tile store
#pragma unroll
  for (int mt = 0; mt < 4; mt++)
#pragma unroll
    for (int ft = 0; ft < 4; ft++) {
      int cl = wf * 64 + ft * 16 + l15;
      int c = cl >> 3, u = cl & 7;
#pragma unroll
      for (int r = 0; r < 4; r++) {
        int rl = wm * 64 + mt * 16 + quad * 4 + r;
        int slot = (c & 8) | ((c ^ rl) & 7);
        Od[rl * 128 + slot * 8 + u] = f2b(o[mt][ft][r]);
      }
    }
  __syncthreads();  // Od complete

  {
    // tile-major A2 -- tile (bx, by) at offset (bx*4+by)*16384
    ushort_t* a2g = A2 + ((long)bx * 4 + by) * 16384;
#pragma unroll
    for (int s = 0; s < 8; ++s) {
      int off = s * 2048 + tid * 8;
      int row = off >> 7;
      int c2 = (off & 127) >> 3;
      int slot = (c2 & 8) | ((c2 ^ row) & 7);
      *(short8*)(a2g + off) = *(const short8*)(Od + row * 128 + slot * 8);
    }
  }

  // block GN stats reduction
  for (int s = 32; s > 0; s >>= 1) {
    lsum += __shfl_xor(lsum, s);
    lss += __shfl_xor(lss, s);
  }
  if (lane == 0) {
    red[wv * 2] = lsum;
    red[wv * 2 + 1] = lss;
  }
  __syncthreads();
  if (tid == 0) {
    float a = 0.f, c = 0.f;
    for (int w2 = 0; w2 < 4; w2++) {
      a += red[w2 * 2];
      c += red[w2 * 2 + 1];
    }
    atomicAdd(&gstats[b * 2], a);
    atomicAdd(&gstats[b * 2 + 1], c);
  }
}

// ---------------------------------------------------------------------------
// Final GEMM, 2-phase pipelined (BK=32 dbuf): out[M,256] = A2@w2T^T with
// GN epilogue; mu/rs from gstats (finalize fused). A2 tile-major.
// 64-row tiles, grid dim3(2, 512): 4 blk/CU, col-tile pair sharing an
// A2 row-panel are adjacent block IDs (same XCD).
// ---------------------------------------------------------------------------
__global__ __launch_bounds__(256, 4) void gemm_out(
    const ushort_t* __restrict__ A, const ushort_t* __restrict__ Bt,
    float* __restrict__ C, const float* __restrict__ gstats,
    const float* __restrict__ gw1, const float* __restrict__ bias2) {
  __shared__ __align__(16) char lds[24576];  // 2 x (4KB A + 8KB B)
  int tid = threadIdx.x;
  int bxc = blockIdx.x;  // 0..1   col tile (fast dim -> XCD pairing)
  int byr = blockIdx.y;  // 0..511 row tile (64 rows)
  long m0 = (long)byr * 64;
  long f0 = (long)bxc * 128;
  int wv = tid >> 6, lane = tid & 63;
  int wm = wv & 1, wf = wv >> 1;
  int l15 = lane & 15, quad = lane >> 4;

  floatx4 acc[2][4];
  floatx4 zero = {0.f, 0.f, 0.f, 0.f};
  for (int i = 0; i < 2; i++)
    for (int j = 0; j < 4; j++) acc[i][j] = zero;

  auto stage = [&](int p, int k0) {
    ushort_t* Ab = (ushort_t*)(lds + p * 12288);
    ushort_t* Bb = Ab + 2048;  // A is 4KB
    // tile-major A2: token-tile byr>>1, col-tile k0>>7, row (byr&1)*64+r
    const ushort_t* At = A + ((long)(byr >> 1) * 4 + (k0 >> 7)) * 16384 +
                         (long)(byr & 1) * 64 * 128 + (k0 & 127);
    {
      int row = tid >> 2, kc = tid & 3;
      int gc = kc ^ (row & 3);
      load_lds16(At + row * 128 + gc * 8, Ab + tid * 8);
    }
#pragma unroll
    for (int r = 0; r < 2; ++r) {
      int chunk = r * 256 + tid;
      int row = chunk >> 2, kc = chunk & 3;
      int gc = kc ^ (row & 3);
      load_lds16(Bt + (f0 + row) * 512 + k0 + gc * 8, Bb + chunk * 8);
    }
  };

  stage(0, 0);
  __syncthreads();
  for (int t = 0; t < 16; ++t) {
    int p = t & 1;
    if (t < 15) stage(p ^ 1, (t + 1) * 32);  // prefetch next tile
    ushort_t* Ab = (ushort_t*)(lds + p * 12288);
    ushort_t* Bb = Ab + 2048;
    short8 af[2], bfr[4];
#pragma unroll
    for (int mt = 0; mt < 2; mt++) {
      int row = wm * 32 + mt * 16 + l15;
      int slot = quad ^ (row & 3);
      af[mt] = *(const short8*)(Ab + row * 32 + slot * 8);
    }
#pragma unroll
    for (int ft = 0; ft < 4; ft++) {
      int rowb = wf * 64 + ft * 16 + l15;
      int slot = quad ^ (rowb & 3);
      bfr[ft] = *(const short8*)(Bb + rowb * 32 + slot * 8);
    }
#pragma unroll
    for (int mt = 0; mt < 2; mt++)
#pragma unroll
      for (int ft = 0; ft < 4; ft++)
        acc[mt][ft] = __builtin_amdgcn_mfma_f32_16x16x32_bf16(
            af[mt], bfr[ft], acc[mt][ft], 0, 0, 0);
    __syncthreads();
  }

  // GN epilogue: mu/rs from gstats (finalize_murs fused)
  int b = (int)(m0 >> 12);
  float cnt = 4096.f * 512.f;
  float mu = gstats[b * 2] / cnt;
  float var = gstats[b * 2 + 1] / cnt - mu * mu;
  float rsv = rsqrtf(var + 1e-5f);
#pragma unroll
  for (int mt = 0; mt < 2; mt++)
#pragma unroll
    for (int ft = 0; ft < 4; ft++) {
      long col = f0 + wf * 64 + ft * 16 + l15;
      float c1 = bias2[col] - rsv * mu * gw1[col];
#pragma unroll
      for (int r = 0; r < 4; r++) {
        long row = m0 + wm * 32 + mt * 16 + quad * 4 + r;
        C[row * 256 + col] = rsv * acc[mt][ft][r] + c1;
      }
    }
}

// ---------------------------------------------------------------------------
extern "C" void kernel_launch(void* const* d_in, const int* in_sizes, int n_in,
                              void* d_out, int out_size, void* d_ws,
                              size_t ws_size, hipStream_t stream) {
  const float* x = (const float*)d_in[0];
  const float* w_qkv = (const float*)d_in[1];
  const float* gn_scale = (const float*)d_in[2];
  const float* gn_bias = (const float*)d_in[3];
  const float* w_out = (const float*)d_in[4];
  const float* b_out = (const float*)d_in[5];
  float* out = (float*)d_out;

  char* w = (char*)d_ws;
  ushort_t* xb = (ushort_t*)(w + 0);             // 16777216 B (32768x256 bf16)
  ushort_t* A2 = (ushort_t*)(w + 16777216);      // 33554432 B (tile-major)
  float* ctxP = (float*)(w + 50331648);          // 33554432 B (32*64*4096 f32)
  float* ksumP = (float*)(w + 83886080);         // 524288 B (32*64*64 f32)
  ushort_t* wqkvT = (ushort_t*)(w + 84410368);   // 786432 B (1536x256 bf16)
  ushort_t* w2T = (ushort_t*)(w + 85196800);     // 262144 B (512x256->bf16 T)
  ushort_t* ctxB = (ushort_t*)(w + 85458944);    // 524288 B (64x4096 bf16)
  float* gstats = (float*)(w + 85983232);        // 64 B
  unsigned int* done = (unsigned int*)(w + 85983296);  // 256 B (64 ctrs)
  float* bias2 = (float*)(w + 85983616);         // 1024 B
  float* gw1 = (float*)(w + 85984640);           // 1024 B

  // zero gstats + done counters (re-zeroed on every graph replay)
  hipMemsetAsync(gstats, 0, 320, stream);

  // fused: cast + both transposes + prep_gw
  prep_all<<<8705, 256, 0, stream>>>(x, w_qkv, gn_scale, gn_bias, w_out,
                                     b_out, xb, wqkvT, w2T, gw1, bias2);
  // fused k/v GEMM + exp + ctx partials + last-block reduce -> ctxB
  kvctx_kernel<<<2048, 256, 0, stream>>>(xb, wqkvT, ctxP, ksumP, ctxB, done);
  // fused q-GEMM + softmax + P@ctx -> A2 (tile-major) + GN stats
  qattn_kernel<<<dim3(256, 4), 256, 0, stream>>>(xb, wqkvT, ctxB, A2, gstats);
  // final GEMM: 64-row tiles, XCD-paired col tiles, GN + finalize fused
  gemm_out<<<dim3(2, 512), 256, 0, stream>>>(A2, w2T, out, gstats, gw1,
                                             bias2);
}

// Round 14
// 219.892 us; speedup vs baseline: 2.5729x; 2.5729x over previous
//
#include <hip/hip_runtime.h>

// LinearAttention (fp32 in/out, bf16 internal MFMA):
// x(8,64,64,256) f32, w_qkv(256,1536) f32, gn_scale/bias(512) f32,
// w_out(512,256) f32, b_out(256) f32 -> out(8,64,64,256) f32
// B=8, N=4096 tokens/batch, HEADS=8, DH=64, HID=512, DIM=256.
//
// Softmaxes WITHOUT max subtraction (|q|,|k| <~ 6, exp fp32-safe).
// R2: kvctx fuses kv-GEMM + exp + ctx partials (kvT eliminated).
// R5: XCD co-location for kvctx. R6: 2-phase pipelined K-loops (BK=32
// dbuf). R7: prep fused, finalize folded into final GEMM (5 launches).
// R9 (cooperative) FAILED under graph capture. R10 (kvctx regrid)
// REGRESSED (XCD sharing collapsed) -- kvctx grid is FROZEN at 2048.
// R11: tile-major A2. R12: gemm_out 64-row tiles, dim3(2,512).
// R13 (atomic last-block reduce) REGRESSED 10x (per-block device fences
// serialize) -- REVERTED. R14 == R12 verbatim (best measured: 222.2us).
// GN folded into final GEMM.

typedef unsigned short ushort_t;
typedef __attribute__((ext_vector_type(8))) short short8;
typedef __attribute__((ext_vector_type(4))) float floatx4;

__device__ __forceinline__ ushort_t f2b(float f) {
  unsigned int i;
  __builtin_memcpy(&i, &f, 4);
  unsigned int r = (i + 0x7FFFu + ((i >> 16) & 1u)) >> 16;
  return (ushort_t)r;
}

// async 16B global->LDS copy (HW dest = wave-uniform base + lane*16)
__device__ __forceinline__ void load_lds16(const ushort_t* g, ushort_t* l) {
  __builtin_amdgcn_global_load_lds(
      (const __attribute__((address_space(1))) unsigned int*)g,
      (__attribute__((address_space(3))) unsigned int*)l, 16, 0, 0);
}

// ---------------------------------------------------------------------------
// FUSED prep: blocks [0,8192) cast x->xb; [8192,8576) transpose w_qkv;
// [8576,8704) transpose w_out (gn_scale-folded); [8704] prep_gw.
// ---------------------------------------------------------------------------
__global__ __launch_bounds__(256) void prep_all(
    const float* __restrict__ x, const float* __restrict__ w_qkv,
    const float* __restrict__ gn_scale, const float* __restrict__ gn_bias,
    const float* __restrict__ w_out, const float* __restrict__ b_out,
    ushort_t* __restrict__ xb, ushort_t* __restrict__ wqkvT,
    ushort_t* __restrict__ w2T, float* __restrict__ gw1,
    float* __restrict__ bias2) {
  __shared__ ushort_t t[32][33];
  int bid = blockIdx.x;
  if (bid < 8192) {  // cast f32 -> bf16
    long i = ((long)bid * 256 + threadIdx.x) * 4;
    float4 v = *(const float4*)(x + i);
    ushort4 o;
    o.x = f2b(v.x);
    o.y = f2b(v.y);
    o.z = f2b(v.z);
    o.w = f2b(v.w);
    *(ushort4*)(xb + i) = o;
    return;
  }
  bid -= 8192;
  if (bid < 384) {  // transpose w_qkv (256x1536) -> wqkvT (1536x256)
    int c0 = (bid % 48) * 32, r0 = (bid / 48) * 32;
    int tx = threadIdx.x & 31, ty = threadIdx.x >> 5;
    for (int i = 0; i < 32; i += 8)
      t[ty + i][tx] = f2b(w_qkv[(long)(r0 + ty + i) * 1536 + c0 + tx]);
    __syncthreads();
    for (int i = 0; i < 32; i += 8)
      wqkvT[(long)(c0 + ty + i) * 256 + r0 + tx] = t[tx][ty + i];
    return;
  }
  bid -= 384;
  if (bid < 128) {  // transpose w_out (512x256) -> w2T, gn_scale-folded
    int c0 = (bid % 8) * 32, r0 = (bid / 8) * 32;
    int tx = threadIdx.x & 31, ty = threadIdx.x >> 5;
    for (int i = 0; i < 32; i += 8) {
      float s = gn_scale[r0 + ty + i];
      t[ty + i][tx] = f2b(w_out[(long)(r0 + ty + i) * 256 + c0 + tx] * s);
    }
    __syncthreads();
    for (int i = 0; i < 32; i += 8)
      w2T[(long)(c0 + ty + i) * 512 + r0 + tx] = t[tx][ty + i];
    return;
  }
  // last block: prep_gw (c = 0..255)
  int c = threadIdx.x;
  float g1 = 0.f, b2 = 0.f;
  for (int f = 0; f < 512; ++f) {
    float w = w_out[f * 256 + c];
    g1 += gn_scale[f] * w;
    b2 += gn_bias[f] * w;
  }
  gw1[c] = g1;
  bias2[c] = b2 + b_out[c];
}

// ---------------------------------------------------------------------------
// FUSED k/v-GEMM + exp + ctx-partial, 2-phase pipelined. Grid 2048 1-D:
//   gid = (b*32+cy) + 256*h  ->  gid%8 = cy%8, head-blocks sharing an xb
// slice co-locate on one XCD. K-loop: 8 iters BK=32, dbuf in 32KB; iter t
// stages t+1 THEN computes t; single barrier/iter. Epilogue (aliases
// staging): exp(k) in-register, ctx-swizzled kTs/vTs round trip, ctx MFMA
// (+ones ksum), NON-ATOMIC partials (32 chunks).
// DO NOT retune this grid: R10's 1024-block variant collapsed L2 sharing
// (FETCH 52->126MB). This is the best measured config.
// ---------------------------------------------------------------------------
__global__ __launch_bounds__(256, 4) void kvctx_kernel(
    const ushort_t* __restrict__ xb, const ushort_t* __restrict__ wqkvT,
    float* __restrict__ ctxP, float* __restrict__ ksumP) {
  __shared__ __align__(16) char lds[32768];
  ushort_t* kTs = (ushort_t*)lds;            // [64 d][128 n] (epilogue alias)
  ushort_t* vTs = (ushort_t*)(lds + 16384);  // [64 e][128 n]

  int gid = blockIdx.x;
  int h = gid >> 8;      // 0..7
  int c0i = gid & 255;   // b*32 + cy
  int b = c0i >> 5;      // 0..7
  int cy = c0i & 31;     // 0..31
  int bh = b * 8 + h;
  int tid = threadIdx.x, wv = tid >> 6, lane = tid & 63;
  int wm = wv & 1, wfk = wv >> 1;  // token half / k-vs-v half
  int l15 = lane & 15, quad = lane >> 4;
  long m0 = (long)b * 4096 + cy * 128;

  floatx4 zero = {0.f, 0.f, 0.f, 0.f};
  floatx4 acc[4][4];
  for (int i = 0; i < 4; i++)
    for (int j = 0; j < 4; j++) acc[i][j] = zero;

  auto stage = [&](int p, int k0) {
    ushort_t* Ab = (ushort_t*)(lds + p * 16384);
    ushort_t* Bb = Ab + 4096;  // +8KB
#pragma unroll
    for (int r = 0; r < 2; ++r) {
      int chunk = r * 256 + tid;
      int row = chunk >> 2, kc = chunk & 3;
      int gc = kc ^ (row & 3);
      long arow = (row < 64 ? 512 : 960) + h * 64 + row;
      load_lds16(wqkvT + arow * 256 + k0 + gc * 8, Ab + chunk * 8);
      load_lds16(xb + (m0 + row) * 256 + k0 + gc * 8, Bb + chunk * 8);
    }
  };

  stage(0, 0);
  __syncthreads();
#pragma unroll
  for (int t = 0; t < 8; ++t) {
    int p = t & 1;
    if (t < 7) stage(p ^ 1, (t + 1) * 32);  // prefetch next tile
    ushort_t* Ab = (ushort_t*)(lds + p * 16384);
    ushort_t* Bb = Ab + 4096;
    short8 af[4], bfr[4];
#pragma unroll
    for (int mt = 0; mt < 4; mt++) {
      int row = wfk * 64 + mt * 16 + l15;
      int slot = quad ^ (row & 3);
      af[mt] = *(const short8*)(Ab + row * 32 + slot * 8);
    }
#pragma unroll
    for (int ft = 0; ft < 4; ft++) {
      int rowb = wm * 64 + ft * 16 + l15;
      int slot = quad ^ (rowb & 3);
      bfr[ft] = *(const short8*)(Bb + rowb * 32 + slot * 8);
    }
#pragma unroll
    for (int mt = 0; mt < 4; mt++)
#pragma unroll
      for (int ft = 0; ft < 4; ft++)
        acc[mt][ft] = __builtin_amdgcn_mfma_f32_16x16x32_bf16(
            af[mt], bfr[ft], acc[mt][ft], 0, 0, 0);
    __syncthreads();  // prefetch landed + everyone done reading buf p
  }
  // loop ended with barrier: staging dead, reusable as kTs/vTs

  // write kv tile into ctx-swizzled LDS layout; exp on the k half.
  {
    ushort_t* T = wfk ? vTs : kTs;
#pragma unroll
    for (int mt = 0; mt < 4; mt++)
#pragma unroll
      for (int ft = 0; ft < 4; ft++) {
        int n = wm * 64 + ft * 16 + l15;
        int c = n >> 3, u = n & 7;
#pragma unroll
        for (int r = 0; r < 4; r++) {
          int d = mt * 16 + quad * 4 + r;
          float v = acc[mt][ft][r];
          if (!wfk) v = __expf(v);
          int slot = (c & 8) | ((c ^ d) & 7);
          T[d * 128 + slot * 8 + u] = f2b(v);
        }
      }
  }
  __syncthreads();  // kTs/vTs visible to all waves

  // ctx partial: ctx[d][e] = sum_n exp(k[d,n]) * v[e,n]; ksum via ones-MFMA
  floatx4 cacc[4], acc1;
  for (int i = 0; i < 4; i++) cacc[i] = zero;
  acc1 = zero;
  short8 ones;
#pragma unroll
  for (int u = 0; u < 8; ++u) ones[u] = (short)0x3F80;  // bf16 1.0
#pragma unroll
  for (int ks = 0; ks < 4; ++ks) {
    int d = wv * 16 + l15;
    int cidx = ks * 4 + quad;
    int sa = (cidx & 8) | ((cidx ^ d) & 7);
    short8 a = *(const short8*)(kTs + d * 128 + sa * 8);
    short8 bf[4];
#pragma unroll
    for (int ft = 0; ft < 4; ++ft) {
      int e = ft * 16 + l15;
      int sb = (cidx & 8) | ((cidx ^ e) & 7);
      bf[ft] = *(const short8*)(vTs + e * 128 + sb * 8);
    }
#pragma unroll
    for (int ft = 0; ft < 4; ++ft)
      cacc[ft] = __builtin_amdgcn_mfma_f32_16x16x32_bf16(a, bf[ft], cacc[ft],
                                                         0, 0, 0);
    acc1 = __builtin_amdgcn_mfma_f32_16x16x32_bf16(a, ones, acc1, 0, 0, 0);
  }
  float* cb = ctxP + ((long)cy * 64 + bh) * 4096;
#pragma unroll
  for (int ft = 0; ft < 4; ++ft)
    *(floatx4*)&cb[(ft * 16 + l15) * 64 + wv * 16 + quad * 4] = cacc[ft];
  if (l15 == 0) {
    float* kb = ksumP + ((long)cy * 64 + bh) * 64;
    *(floatx4*)&kb[wv * 16 + quad * 4] = acc1;
  }
}

// ---------------------------------------------------------------------------
// Fold 32 chunk-partials and bake qattn's B operand:
// ctxB[bh][e*64 + slot*8 + u] = bf16( (sum_c ctxP) * kinv[d] ),
//   d = chunk*8+u, slot = chunk ^ (e&7)  (MFMA-swizzled bf16 layout).
// ---------------------------------------------------------------------------
__global__ __launch_bounds__(256) void reduce_kernel(
    const float* __restrict__ ctxP, const float* __restrict__ ksumP,
    ushort_t* __restrict__ ctxB) {
  int bid = blockIdx.x;
  int bh = bid >> 4;
  int j = (bid & 15) * 256 + threadIdx.x;  // 0..4095 within bh
  int e = j >> 6, d = j & 63;
  float ks = 0.f;
#pragma unroll
  for (int c = 0; c < 32; ++c) ks += ksumP[((long)c * 64 + bh) * 64 + d];
  float s = 0.f;
#pragma unroll
  for (int c = 0; c < 32; ++c) s += ctxP[((long)c * 64 + bh) * 4096 + j];
  int slot = (d >> 3) ^ (e & 7);
  ctxB[(long)bh * 4096 + e * 64 + slot * 8 + (d & 7)] = f2b(s / ks);
}

// ---------------------------------------------------------------------------
// FUSED q-GEMM + q-softmax + P@ctx, 2-phase pipelined K-loop (BK=32 dbuf).
// Grid (256 token-tiles, 4 col-tiles), 4 blk/CU. Epilogue: ctxB frags
// global->reg; exp in-register; butterfly row-sums; 0.125/s folded into P
// bf16 write; P round-trip via per-wave LDS; P@ctx MFMA (K=64); o tile
// repacked via LDS (Od). A2 TILE-MAJOR [bx][by][128][128] -- each block
// stores one contiguous 32KB tile (R8-validated).
// ---------------------------------------------------------------------------
__global__ __launch_bounds__(256, 4) void qattn_kernel(
    const ushort_t* __restrict__ xb, const ushort_t* __restrict__ wqT,
    const ushort_t* __restrict__ ctxB, ushort_t* __restrict__ A2,
    float* __restrict__ gstats) {
  __shared__ __align__(16) char lds[32800];
  ushort_t* P = (ushort_t*)lds;        // [2][128][64] per-wave scratch
  ushort_t* Od = (ushort_t*)lds;       // [128][128] repack (epilogue)
  float* red = (float*)(lds + 32768);  // [8]

  int tid = threadIdx.x;
  int bx = blockIdx.x, by = blockIdx.y;
  long m0 = (long)bx * 128;
  long f0 = (long)by * 128;
  int wv = tid >> 6, lane = tid & 63;
  int wm = wv & 1, wf = wv >> 1;
  int l15 = lane & 15, quad = lane >> 4;
  int b = bx >> 5;  // 32 tiles of 128 tokens per batch

  floatx4 acc[4][4];
  floatx4 zero = {0.f, 0.f, 0.f, 0.f};
  for (int i = 0; i < 4; i++)
    for (int j = 0; j < 4; j++) acc[i][j] = zero;

  auto stage = [&](int p, int k0) {
    ushort_t* Ab = (ushort_t*)(lds + p * 16384);
    ushort_t* Bb = Ab + 4096;  // +8KB
#pragma unroll
    for (int r = 0; r < 2; ++r) {
      int chunk = r * 256 + tid;
      int row = chunk >> 2, kc = chunk & 3;
      int gc = kc ^ (row & 3);
      load_lds16(xb + (m0 + row) * 256 + k0 + gc * 8, Ab + chunk * 8);
      load_lds16(wqT + (f0 + row) * 256 + k0 + gc * 8, Bb + chunk * 8);
    }
  };

  stage(0, 0);
  __syncthreads();
#pragma unroll
  for (int t = 0; t < 8; ++t) {
    int p = t & 1;
    if (t < 7) stage(p ^ 1, (t + 1) * 32);  // prefetch next tile
    ushort_t* Ab = (ushort_t*)(lds + p * 16384);
    ushort_t* Bb = Ab + 4096;
    short8 af[4], bfr[4];
#pragma unroll
    for (int mt = 0; mt < 4; mt++) {
      int row = wm * 64 + mt * 16 + l15;
      int slot = quad ^ (row & 3);
      af[mt] = *(const short8*)(Ab + row * 32 + slot * 8);
    }
#pragma unroll
    for (int ft = 0; ft < 4; ft++) {
      int rowb = wf * 64 + ft * 16 + l15;
      int slot = quad ^ (rowb & 3);
      bfr[ft] = *(const short8*)(Bb + rowb * 32 + slot * 8);
    }
#pragma unroll
    for (int mt = 0; mt < 4; mt++)
#pragma unroll
      for (int ft = 0; ft < 4; ft++)
        acc[mt][ft] = __builtin_amdgcn_mfma_f32_16x16x32_bf16(
            af[mt], bfr[ft], acc[mt][ft], 0, 0, 0);
    __syncthreads();
  }
  // loop ended with barrier: staging dead, safe to reuse as P

  // ctxB fragments (k0=0 half) global->reg (L2-resident)
  const ushort_t* cg = ctxB + ((long)(b * 8 + by * 2 + wf)) * 4096;
  short8 cfr0[4];
#pragma unroll
  for (int ft = 0; ft < 4; ++ft) {
    int e = ft * 16 + l15;
    int slot = quad ^ (e & 7);
    cfr0[ft] = *(const short8*)(cg + e * 64 + slot * 8);
  }

  // exp in-register + row sums (butterfly over l15) -> rs = 0.125/s
  float rs[4][4];
#pragma unroll
  for (int mt = 0; mt < 4; mt++)
#pragma unroll
    for (int r = 0; r < 4; r++) rs[mt][r] = 0.f;
#pragma unroll
  for (int mt = 0; mt < 4; mt++)
#pragma unroll
    for (int ft = 0; ft < 4; ft++)
#pragma unroll
      for (int r = 0; r < 4; r++) {
        float e = __expf(acc[mt][ft][r]);
        acc[mt][ft][r] = e;
        rs[mt][r] += e;
      }
#pragma unroll
  for (int mt = 0; mt < 4; mt++)
#pragma unroll
    for (int r = 0; r < 4; r++) {
      float t = rs[mt][r];
      t += __shfl_xor(t, 1);
      t += __shfl_xor(t, 2);
      t += __shfl_xor(t, 4);
      t += __shfl_xor(t, 8);
      rs[mt][r] = 0.125f / t;
    }

  // write P = exp * rs to per-wave LDS scratch in swizzled A-layout
  {
    ushort_t* Pw = P + wf * 8192;
#pragma unroll
    for (int mt = 0; mt < 4; mt++)
#pragma unroll
      for (int ft = 0; ft < 4; ft++) {
        int d = ft * 16 + l15;
#pragma unroll
        for (int r = 0; r < 4; r++) {
          int row = wm * 64 + mt * 16 + quad * 4 + r;
          int slot = (d >> 3) ^ (row & 7);
          Pw[row * 64 + slot * 8 + (d & 7)] = f2b(acc[mt][ft][r] * rs[mt][r]);
        }
      }
  }

  // ctxB fragments (k0=1 half)
  short8 cfr1[4];
#pragma unroll
  for (int ft = 0; ft < 4; ++ft) {
    int e = ft * 16 + l15;
    int slot = (4 + quad) ^ (e & 7);
    cfr1[ft] = *(const short8*)(cg + e * 64 + slot * 8);
  }

  // P@ctx MFMA: K=64. P per-wave private -> no barrier needed.
  floatx4 o[4][4];
  for (int i = 0; i < 4; i++)
    for (int j = 0; j < 4; j++) o[i][j] = zero;
  {
    const ushort_t* Pr = P + wf * 8192;
    short8 af[4];
#pragma unroll
    for (int mt = 0; mt < 4; mt++) {
      int row = wm * 64 + mt * 16 + l15;
      int slot = quad ^ (row & 7);
      af[mt] = *(const short8*)(Pr + row * 64 + slot * 8);
    }
#pragma unroll
    for (int mt = 0; mt < 4; mt++)
#pragma unroll
      for (int ft = 0; ft < 4; ft++)
        o[mt][ft] = __builtin_amdgcn_mfma_f32_16x16x32_bf16(af[mt], cfr0[ft],
                                                            o[mt][ft], 0, 0,
                                                            0);
#pragma unroll
    for (int mt = 0; mt < 4; mt++) {
      int row = wm * 64 + mt * 16 + l15;
      int slot = (4 + quad) ^ (row & 7);
      af[mt] = *(const short8*)(Pr + row * 64 + slot * 8);
    }
#pragma unroll
    for (int mt = 0; mt < 4; mt++)
#pragma unroll
      for (int ft = 0; ft < 4; ft++)
        o[mt][ft] = __builtin_amdgcn_mfma_f32_16x16x32_bf16(af[mt], cfr1[ft],
                                                            o[mt][ft], 0, 0,
                                                            0);
  }

  // GN stats from o (these ARE the final A2 values)
  float lsum = 0.f, lss = 0.f;
#pragma unroll
  for (int mt = 0; mt < 4; mt++)
#pragma unroll
    for (int ft = 0; ft < 4; ft++)
#pragma unroll
      for (int r = 0; r < 4; r++) {
        float v = o[mt][ft][r];
        lsum += v;
        lss += v * v;
      }

  __syncthreads();  // all P reads done; P region reusable as Od repack

  // repack o into Od[128][128] (chunk-swizzled), then contiguous tile store
#pragma unroll
  for (int mt = 0; mt < 4; mt++)
#pragma unroll
    for (int ft = 0; ft < 4; ft++) {
      int cl = wf * 64 + ft * 16 + l15;
      int c = cl >> 3, u = cl & 7;
#pragma unroll
      for (int r = 0; r < 4; r++) {
        int rl = wm * 64 + mt * 16 + quad * 4 + r;
        int slot = (c & 8) | ((c ^ rl) & 7);
        Od[rl * 128 + slot * 8 + u] = f2b(o[mt][ft][r]);
      }
    }
  __syncthreads();  // Od complete

  {
    // tile-major A2 -- tile (bx, by) at offset (bx*4+by)*16384
    ushort_t* a2g = A2 + ((long)bx * 4 + by) * 16384;
#pragma unroll
    for (int s = 0; s < 8; ++s) {
      int off = s * 2048 + tid * 8;
      int row = off >> 7;
      int c2 = (off & 127) >> 3;
      int slot = (c2 & 8) | ((c2 ^ row) & 7);
      *(short8*)(a2g + off) = *(const short8*)(Od + row * 128 + slot * 8);
    }
  }

  // block GN stats reduction
  for (int s = 32; s > 0; s >>= 1) {
    lsum += __shfl_xor(lsum, s);
    lss += __shfl_xor(lss, s);
  }
  if (lane == 0) {
    red[wv * 2] = lsum;
    red[wv * 2 + 1] = lss;
  }
  __syncthreads();
  if (tid == 0) {
    float a = 0.f, c = 0.f;
    for (int w2 = 0; w2 < 4; w2++) {
      a += red[w2 * 2];
      c += red[w2 * 2 + 1];
    }
    atomicAdd(&gstats[b * 2], a);
    atomicAdd(&gstats[b * 2 + 1], c);
  }
}

// ---------------------------------------------------------------------------
// Final GEMM, 2-phase pipelined (BK=32 dbuf): out[M,256] = A2@w2T^T with
// GN epilogue; mu/rs from gstats (finalize fused). A2 tile-major.
// 64-row tiles, grid dim3(2, 512): 4 blk/CU, col-tile pair sharing an
// A2 row-panel are adjacent block IDs (same XCD).
// ---------------------------------------------------------------------------
__global__ __launch_bounds__(256, 4) void gemm_out(
    const ushort_t* __restrict__ A, const ushort_t* __restrict__ Bt,
    float* __restrict__ C, const float* __restrict__ gstats,
    const float* __restrict__ gw1, const float* __restrict__ bias2) {
  __shared__ __align__(16) char lds[24576];  // 2 x (4KB A + 8KB B)
  int tid = threadIdx.x;
  int bxc = blockIdx.x;  // 0..1   col tile (fast dim -> XCD pairing)
  int byr = blockIdx.y;  // 0..511 row tile (64 rows)
  long m0 = (long)byr * 64;
  long f0 = (long)bxc * 128;
  int wv = tid >> 6, lane = tid & 63;
  int wm = wv & 1, wf = wv >> 1;
  int l15 = lane & 15, quad = lane >> 4;

  floatx4 acc[2][4];
  floatx4 zero = {0.f, 0.f, 0.f, 0.f};
  for (int i = 0; i < 2; i++)
    for (int j = 0; j < 4; j++) acc[i][j] = zero;

  auto stage = [&](int p, int k0) {
    ushort_t* Ab = (ushort_t*)(lds + p * 12288);
    ushort_t* Bb = Ab + 2048;  // A is 4KB
    // tile-major A2: token-tile byr>>1, col-tile k0>>7, row (byr&1)*64+r
    const ushort_t* At = A + ((long)(byr >> 1) * 4 + (k0 >> 7)) * 16384 +
                         (long)(byr & 1) * 64 * 128 + (k0 & 127);
    {
      int row = tid >> 2, kc = tid & 3;
      int gc = kc ^ (row & 3);
      load_lds16(At + row * 128 + gc * 8, Ab + tid * 8);
    }
#pragma unroll
    for (int r = 0; r < 2; ++r) {
      int chunk = r * 256 + tid;
      int row = chunk >> 2, kc = chunk & 3;
      int gc = kc ^ (row & 3);
      load_lds16(Bt + (f0 + row) * 512 + k0 + gc * 8, Bb + chunk * 8);
    }
  };

  stage(0, 0);
  __syncthreads();
  for (int t = 0; t < 16; ++t) {
    int p = t & 1;
    if (t < 15) stage(p ^ 1, (t + 1) * 32);  // prefetch next tile
    ushort_t* Ab = (ushort_t*)(lds + p * 12288);
    ushort_t* Bb = Ab + 2048;
    short8 af[2], bfr[4];
#pragma unroll
    for (int mt = 0; mt < 2; mt++) {
      int row = wm * 32 + mt * 16 + l15;
      int slot = quad ^ (row & 3);
      af[mt] = *(const short8*)(Ab + row * 32 + slot * 8);
    }
#pragma unroll
    for (int ft = 0; ft < 4; ft++) {
      int rowb = wf * 64 + ft * 16 + l15;
      int slot = quad ^ (rowb & 3);
      bfr[ft] = *(const short8*)(Bb + rowb * 32 + slot * 8);
    }
#pragma unroll
    for (int mt = 0; mt < 2; mt++)
#pragma unroll
      for (int ft = 0; ft < 4; ft++)
        acc[mt][ft] = __builtin_amdgcn_mfma_f32_16x16x32_bf16(
            af[mt], bfr[ft], acc[mt][ft], 0, 0, 0);
    __syncthreads();
  }

  // GN epilogue: mu/rs from gstats (finalize_murs fused)
  int b = (int)(m0 >> 12);
  float cnt = 4096.f * 512.f;
  float mu = gstats[b * 2] / cnt;
  float var = gstats[b * 2 + 1] / cnt - mu * mu;
  float rsv = rsqrtf(var + 1e-5f);
#pragma unroll
  for (int mt = 0; mt < 2; mt++)
#pragma unroll
    for (int ft = 0; ft < 4; ft++) {
      long col = f0 + wf * 64 + ft * 16 + l15;
      float c1 = bias2[col] - rsv * mu * gw1[col];
#pragma unroll
      for (int r = 0; r < 4; r++) {
        long row = m0 + wm * 32 + mt * 16 + quad * 4 + r;
        C[row * 256 + col] = rsv * acc[mt][ft][r] + c1;
      }
    }
}

// ---------------------------------------------------------------------------
extern "C" void kernel_launch(void* const* d_in, const int* in_sizes, int n_in,
                              void* d_out, int out_size, void* d_ws,
                              size_t ws_size, hipStream_t stream) {
  const float* x = (const float*)d_in[0];
  const float* w_qkv = (const float*)d_in[1];
  const float* gn_scale = (const float*)d_in[2];
  const float* gn_bias = (const float*)d_in[3];
  const float* w_out = (const float*)d_in[4];
  const float* b_out = (const float*)d_in[5];
  float* out = (float*)d_out;

  char* w = (char*)d_ws;
  ushort_t* xb = (ushort_t*)(w + 0);            // 16777216 B (32768x256 bf16)
  ushort_t* A2 = (ushort_t*)(w + 16777216);     // 33554432 B (tile-major)
  float* ctxP = (float*)(w + 50331648);         // 33554432 B (32*64*4096 f32)
  float* ksumP = (float*)(w + 83886080);        // 524288 B (32*64*64 f32)
  ushort_t* wqkvT = (ushort_t*)(w + 84410368);  // 786432 B (1536x256 bf16)
  ushort_t* w2T = (ushort_t*)(w + 85196800);    // 262144 B (512x256->bf16 T)
  ushort_t* ctxB = (ushort_t*)(w + 85458944);   // 524288 B (64x4096 bf16)
  float* gstats = (float*)(w + 85983232);       // 64 B
  float* bias2 = (float*)(w + 85983360);        // 1024 B
  float* gw1 = (float*)(w + 85984384);          // 1024 B

  hipMemsetAsync(gstats, 0, 64, stream);

  // fused: cast + both transposes + prep_gw
  prep_all<<<8705, 256, 0, stream>>>(x, w_qkv, gn_scale, gn_bias, w_out,
                                     b_out, xb, wqkvT, w2T, gw1, bias2);
  // fused k/v GEMM + exp + ctx partials (2-phase pipelined, XCD-colocated)
  kvctx_kernel<<<2048, 256, 0, stream>>>(xb, wqkvT, ctxP, ksumP);
  // fold partials -> ctxB (kinv-scaled, bf16, pre-swizzled)
  reduce_kernel<<<1024, 256, 0, stream>>>(ctxP, ksumP, ctxB);
  // fused q-GEMM + softmax + P@ctx -> A2 (tile-major) + GN stats
  qattn_kernel<<<dim3(256, 4), 256, 0, stream>>>(xb, wqkvT, ctxB, A2, gstats);
  // final GEMM: 64-row tiles, XCD-paired col tiles, GN + finalize fused
  gemm_out<<<dim3(2, 512), 256, 0, stream>>>(A2, w2T, out, gstats, gw1,
                                             bias2);
}